// Round 10
// baseline (101.688 us; speedup 1.0000x reference)
//
#include <hip/hip_runtime.h>
#include <hip/hip_bf16.h>

typedef short short8 __attribute__((ext_vector_type(8)));
typedef short short4v __attribute__((ext_vector_type(4)));
typedef float float4v __attribute__((ext_vector_type(4)));
typedef float f32x4 __attribute__((ext_vector_type(4)));

#define NEG_HUGE (-1e30f)
#define QK_SCALE 0.1803368801111204f  /* 0.125 * log2(e) */

__device__ __forceinline__ unsigned short f2bf(float f) {
  union { __hip_bfloat16 h; unsigned short u; } c;
  c.h = __float2bfloat16(f);
  return c.u;
}

#define MFMA16(a, b, c) __builtin_amdgcn_mfma_f32_16x16x32_bf16((a), (b), (c), 0, 0, 0)

// ---------------------------------------------------------------------------
// Kernel 0: W [1024][64] fp32 (x3) -> Wt [3][64][1024] bf16 (transposed).
// Wq additionally scaled by 0.125*log2(e) so attn works in exp2 domain.
// ---------------------------------------------------------------------------
__global__ __launch_bounds__(256) void wtrans_kernel(
    const float* __restrict__ Wk, const float* __restrict__ Wq,
    const float* __restrict__ Wv, unsigned short* __restrict__ Wt) {
  int mat = blockIdx.x >> 4, kb = blockIdx.x & 15;
  const float* W = (mat == 0) ? Wk : ((mat == 1) ? Wq : Wv);
  float qscale = (mat == 1) ? QK_SCALE : 1.0f;
  __shared__ float tile[64][65];
  int tid = threadIdx.x;
  int n = tid & 63, k0 = tid >> 6;
#pragma unroll
  for (int i = 0; i < 16; i++) {
    int k = i * 4 + k0;
    tile[k][n] = W[(kb * 64 + k) * 64 + n];
  }
  __syncthreads();
  int n2 = tid >> 2, c = tid & 3;
  unsigned short tmp[16];
#pragma unroll
  for (int j = 0; j < 16; j++) tmp[j] = f2bf(tile[c * 16 + j][n2] * qscale);
  unsigned short* dst = Wt + (mat * 64 + n2) * 1024 + kb * 64 + c * 16;
  *(short8*)dst = *(short8*)tmp;
  *(short8*)(dst + 8) = *(short8*)(tmp + 8);
}

// ---------------------------------------------------------------------------
// Kernel 1: projection v4 — NO LDS, NO BARRIERS. x[16384][1024] fp32 @
// Wt[3][64][1024] bf16 -> Kb/Qb [16384][64] bf16, Vt (sigma-permuted).
// BM=32, grid 512, 4 waves (wm 0..1 x wn 0..1). Per-lane direct global
// fragment loads (A: 8 fp32 of one x row + cvt; B: 8 bf16 of one Wt row,
// L2-hot). Depth-1 register prefetch; compiler free to pipeline (no syncs).
// ---------------------------------------------------------------------------
__global__ __launch_bounds__(256, 4) void proj_kernel(
    const float* __restrict__ x, const unsigned short* __restrict__ Wt,
    unsigned short* __restrict__ Kb, unsigned short* __restrict__ Qb,
    unsigned short* __restrict__ Vt) {
  int tid = threadIdx.x;
  int w = tid >> 6, lane = tid & 63;
  int wm = w & 1, wn = w >> 1;
  int g = lane >> 4, r = lane & 15;
  int row0 = blockIdx.x * 32;

  const float* xp = &x[(size_t)(row0 + wm * 16 + r) * 1024 + g * 8];
  const unsigned short* wp[6];
#pragma unroll
  for (int nf = 0; nf < 6; nf++)
    wp[nf] = &Wt[(size_t)(wn * 96 + nf * 16 + r) * 1024 + g * 8];

  f32x4 acc[6];
#pragma unroll
  for (int nf = 0; nf < 6; nf++) acc[nf] = (f32x4){0.f, 0.f, 0.f, 0.f};

  // prefetch k = 0
  float4v a_lo = *(const float4v*)(xp);
  float4v a_hi = *(const float4v*)(xp + 4);
  short8 bc[6];
#pragma unroll
  for (int nf = 0; nf < 6; nf++) bc[nf] = *(const short8*)(wp[nf]);

#pragma unroll 4
  for (int k = 0; k < 992; k += 32) {
    // issue next-step loads (no barriers anywhere -> these pipeline freely)
    float4v n_lo = *(const float4v*)(xp + k + 32);
    float4v n_hi = *(const float4v*)(xp + k + 36);
    short8 bn[6];
#pragma unroll
    for (int nf = 0; nf < 6; nf++) bn[nf] = *(const short8*)(wp[nf] + k + 32);
    // convert A and compute current step
    unsigned short t8[8];
    t8[0] = f2bf(a_lo[0]); t8[1] = f2bf(a_lo[1]); t8[2] = f2bf(a_lo[2]); t8[3] = f2bf(a_lo[3]);
    t8[4] = f2bf(a_hi[0]); t8[5] = f2bf(a_hi[1]); t8[6] = f2bf(a_hi[2]); t8[7] = f2bf(a_hi[3]);
    short8 af = *(short8*)t8;
#pragma unroll
    for (int nf = 0; nf < 6; nf++) acc[nf] = MFMA16(af, bc[nf], acc[nf]);
    // rotate
    a_lo = n_lo; a_hi = n_hi;
#pragma unroll
    for (int nf = 0; nf < 6; nf++) bc[nf] = bn[nf];
  }
  // final step (k = 992)
  {
    unsigned short t8[8];
    t8[0] = f2bf(a_lo[0]); t8[1] = f2bf(a_lo[1]); t8[2] = f2bf(a_lo[2]); t8[3] = f2bf(a_lo[3]);
    t8[4] = f2bf(a_hi[0]); t8[5] = f2bf(a_hi[1]); t8[6] = f2bf(a_hi[2]); t8[7] = f2bf(a_hi[3]);
    short8 af = *(short8*)t8;
#pragma unroll
    for (int nf = 0; nf < 6; nf++) acc[nf] = MFMA16(af, bc[nf], acc[nf]);
  }
  // epilogue: row = row0 + wm*16 + g*4 + reg, col = wn*96 + nf*16 + r
#pragma unroll
  for (int nf = 0; nf < 6; nf++) {
    int col = wn * 96 + nf * 16 + r;
    if (col < 128) {
      int mat = col >> 6, h = col & 63;
      unsigned short* dst = (mat == 0) ? Kb : Qb;
#pragma unroll
      for (int reg = 0; reg < 4; reg++) {
        int grow = row0 + wm * 16 + g * 4 + reg;
        dst[(size_t)grow * 64 + h] = f2bf(acc[nf][reg]);
      }
    } else {
      int h = col & 63;
      int grow0 = row0 + wm * 16 + g * 4;
      unsigned short t4[4];
#pragma unroll
      for (int reg = 0; reg < 4; reg++) t4[reg] = f2bf(acc[nf][reg]);
      // sigma permutation within the 64-row block (reg stays contiguous)
      int kv6 = grow0 & 63;
      int nfb = (kv6 >> 4) & 3, gb = (kv6 >> 2) & 3;
      int s0 = (nfb >> 1) * 32 + gb * 8 + (nfb & 1) * 4;
      size_t off = ((size_t)(grow0 >> 12) * 64 + h) * 4096 +
                   ((size_t)(grow0 & 4095) & ~(size_t)63) + s0;
      *(short4v*)&Vt[off] = *(short4v*)t4;
    }
  }
}

// ---------------------------------------------------------------------------
// Kernel 2: causal flash attention v8 (= v6 loop + colocation-balanced qt).
// grid 512, 256 thr = 4 waves kv-split (t%4==w), 32-row q-tile.
// Blocks bi and bi+256 co-reside on the same CU (observed round-robin
// dispatch); qt = (iq<64) ? 64+iq : 127-iq makes each colocated pair's
// ntiles sum exactly 65 -> uniform per-CU work, heavy blocks dispatched
// first. Swapped QK^T + swapped PV with pi-permuted V; P in registers.
// V loads issued AFTER QK^T so their latency hides under softmax.
// ---------------------------------------------------------------------------
__global__ __launch_bounds__(256, 3) void attn_kernel(
    const unsigned short* __restrict__ Kb, const unsigned short* __restrict__ Qb,
    const unsigned short* __restrict__ VtB, float* __restrict__ out) {
  __shared__ float O_l[4][32][68];
  __shared__ float st_l[4][32][2];
  int tid = threadIdx.x;
  int w = tid >> 6, lane = tid & 63;
  int g = lane >> 4, r = lane & 15;
  int bi = blockIdx.x;
  int b = bi & 3, iq = bi >> 2;           // iq 0..127
  int qt = (iq < 64) ? (64 + iq) : (127 - iq);
  int qabs = qt * 32;
  const unsigned short* Kp = Kb + (size_t)b * 4096 * 64;
  const unsigned short* Qp = Qb + (size_t)b * 4096 * 64;
  const unsigned short* Vp = VtB + (size_t)b * 64 * 4096;

  // Q B-operand frags: B[q=mf*16+r][k=h=ks*32+g*8+j]
  short8 qa[2][2];
#pragma unroll
  for (int mf = 0; mf < 2; mf++)
#pragma unroll
    for (int ks = 0; ks < 2; ks++)
      qa[mf][ks] = *(const short8*)&Qp[(size_t)(qabs + mf * 16 + r) * 64 + ks * 32 + g * 8];

  float m_st[2] = {NEG_HUGE, NEG_HUGE};
  float l_ln[2] = {0.f, 0.f};        // per-lane partial row sums
  f32x4 o[4][2];                      // o[nfh][mf]
#pragma unroll
  for (int nfh = 0; nfh < 4; nfh++)
#pragma unroll
    for (int mf = 0; mf < 2; mf++) o[nfh][mf] = (f32x4){0.f, 0.f, 0.f, 0.f};

  int ntiles = (qabs >> 6) + 1;
  for (int t = w; t < ntiles; t += 4) {
    int kvb = t << 6;
    // ---- S^T = K Q^T, K loaded JIT per ks-half ----
    f32x4 s[4][2];
#pragma unroll
    for (int nf = 0; nf < 4; nf++)
#pragma unroll
      for (int mf = 0; mf < 2; mf++) s[nf][mf] = (f32x4){0.f, 0.f, 0.f, 0.f};
#pragma unroll
    for (int ks = 0; ks < 2; ks++) {
      short8 kf[4];
#pragma unroll
      for (int nf = 0; nf < 4; nf++)
        kf[nf] = *(const short8*)&Kp[(size_t)(kvb + nf * 16 + r) * 64 + ks * 32 + g * 8];
#pragma unroll
      for (int nf = 0; nf < 4; nf++) {
        s[nf][0] = MFMA16(kf[nf], qa[0][ks], s[nf][0]);
        s[nf][1] = MFMA16(kf[nf], qa[1][ks], s[nf][1]);
      }
    }
    // ---- V A-fragments issued here: latency hides under softmax ----
    short8 vf[2][4];
#pragma unroll
    for (int ks = 0; ks < 2; ks++)
#pragma unroll
      for (int nfh = 0; nfh < 4; nfh++)
        vf[ks][nfh] = *(const short8*)&Vp[(size_t)(nfh * 16 + r) * 4096 + kvb + ks * 32 + g * 8];
    // ---- causal mask (final tile only) ----
    if (kvb + 63 > qabs) {
#pragma unroll
      for (int mf = 0; mf < 2; mf++) {
        int q = qabs + mf * 16 + r;
#pragma unroll
        for (int nf = 0; nf < 4; nf++)
#pragma unroll
          for (int reg = 0; reg < 4; reg++) {
            int kv = kvb + nf * 16 + g * 4 + reg;
            if (kv > q) s[nf][mf][reg] = NEG_HUGE;
          }
      }
    }
    // ---- row max (in-lane 16 + xor16/xor32), alpha ----
    float alpha[2];
#pragma unroll
    for (int mf = 0; mf < 2; mf++) {
      float m0 = fmaxf(fmaxf(fmaxf(s[0][mf][0], s[0][mf][1]), fmaxf(s[0][mf][2], s[0][mf][3])),
                       fmaxf(fmaxf(s[1][mf][0], s[1][mf][1]), fmaxf(s[1][mf][2], s[1][mf][3])));
      float m1 = fmaxf(fmaxf(fmaxf(s[2][mf][0], s[2][mf][1]), fmaxf(s[2][mf][2], s[2][mf][3])),
                       fmaxf(fmaxf(s[3][mf][0], s[3][mf][1]), fmaxf(s[3][mf][2], s[3][mf][3])));
      float m0a = fmaxf(m0, m1);
      m0a = fmaxf(m0a, __shfl_xor(m0a, 16));
      m0a = fmaxf(m0a, __shfl_xor(m0a, 32));
      float mn = fmaxf(m_st[mf], m0a);
      alpha[mf] = exp2f(m_st[mf] - mn);
      m_st[mf] = mn;
    }
    // ---- P = exp2(S - m) in-place; per-lane partial sums; rescale O ----
#pragma unroll
    for (int mf = 0; mf < 2; mf++) {
      float rs = 0.f;
#pragma unroll
      for (int nf = 0; nf < 4; nf++)
#pragma unroll
        for (int reg = 0; reg < 4; reg++) {
          float p = exp2f(s[nf][mf][reg] - m_st[mf]);
          s[nf][mf][reg] = p;
          rs += p;
        }
      l_ln[mf] = l_ln[mf] * alpha[mf] + rs;
#pragma unroll
      for (int nfh = 0; nfh < 4; nfh++)
#pragma unroll
        for (int reg = 0; reg < 4; reg++) o[nfh][mf][reg] *= alpha[mf];
    }
    // ---- pack P lane-locally (pi layout) and PV ----
#pragma unroll
    for (int ks = 0; ks < 2; ks++)
#pragma unroll
      for (int mf = 0; mf < 2; mf++) {
        union { unsigned u[4]; short8 v; } pb;
        asm("v_cvt_pk_bf16_f32 %0, %1, %2" : "=v"(pb.u[0]) : "v"(s[2 * ks][mf][0]), "v"(s[2 * ks][mf][1]));
        asm("v_cvt_pk_bf16_f32 %0, %1, %2" : "=v"(pb.u[1]) : "v"(s[2 * ks][mf][2]), "v"(s[2 * ks][mf][3]));
        asm("v_cvt_pk_bf16_f32 %0, %1, %2" : "=v"(pb.u[2]) : "v"(s[2 * ks + 1][mf][0]), "v"(s[2 * ks + 1][mf][1]));
        asm("v_cvt_pk_bf16_f32 %0, %1, %2" : "=v"(pb.u[3]) : "v"(s[2 * ks + 1][mf][2]), "v"(s[2 * ks + 1][mf][3]));
#pragma unroll
        for (int nfh = 0; nfh < 4; nfh++)
          o[nfh][mf] = MFMA16(vf[ks][nfh], pb.v, o[nfh][mf]);
      }
  }
  // ---- finalize l (deferred reduction) ----
#pragma unroll
  for (int mf = 0; mf < 2; mf++) {
    float s0 = l_ln[mf];
    s0 += __shfl_xor(s0, 16);
    s0 += __shfl_xor(s0, 32);
    l_ln[mf] = s0;
  }
  // ---- cross-wave merge: store [q][h] (q = mf*16+r, h = nfh*16+g*4+reg) ----
  __syncthreads();
#pragma unroll
  for (int nfh = 0; nfh < 4; nfh++)
#pragma unroll
    for (int mf = 0; mf < 2; mf++)
      *(f32x4*)&O_l[w][mf * 16 + r][nfh * 16 + g * 4] = o[nfh][mf];
  if (g == 0) {
#pragma unroll
    for (int mf = 0; mf < 2; mf++) {
      st_l[w][mf * 16 + r][0] = m_st[mf];
      st_l[w][mf * 16 + r][1] = l_ln[mf];
    }
  }
  __syncthreads();
  {
    int row = tid >> 3, cg = tid & 7;   // row = q (0..31), cg*8 = h block
    float mw[4], lw[4];
#pragma unroll
    for (int ww = 0; ww < 4; ww++) {
      mw[ww] = st_l[ww][row][0];
      lw[ww] = st_l[ww][row][1];
    }
    float mstar = fmaxf(fmaxf(mw[0], mw[1]), fmaxf(mw[2], mw[3]));
    float sc[4], lstar = 0.f;
#pragma unroll
    for (int ww = 0; ww < 4; ww++) { sc[ww] = exp2f(mw[ww] - mstar); lstar += sc[ww] * lw[ww]; }
    float inv = 1.0f / lstar;
    float a0[8];
#pragma unroll
    for (int cc = 0; cc < 8; cc++) a0[cc] = 0.f;
#pragma unroll
    for (int ww = 0; ww < 4; ww++) {
      f32x4 v0 = *(f32x4*)&O_l[ww][row][cg * 8];
      f32x4 v1 = *(f32x4*)&O_l[ww][row][cg * 8 + 4];
#pragma unroll
      for (int e = 0; e < 4; e++) { a0[e] += sc[ww] * v0[e]; a0[4 + e] += sc[ww] * v1[e]; }
    }
    float4v o0, o1;
#pragma unroll
    for (int e = 0; e < 4; e++) { o0[e] = a0[e] * inv; o1[e] = a0[4 + e] * inv; }
    float* op = &out[((size_t)b * 4096 + qabs + row) * 64 + cg * 8];
    *(float4v*)op = o0;
    *(float4v*)(op + 4) = o1;
  }
}

// ---------------------------------------------------------------------------
extern "C" void kernel_launch(void* const* d_in, const int* in_sizes, int n_in,
                              void* d_out, int out_size, void* d_ws, size_t ws_size,
                              hipStream_t stream) {
  (void)in_sizes; (void)n_in; (void)out_size; (void)ws_size;
  const float* x  = (const float*)d_in[0];
  const float* Wk = (const float*)d_in[1];
  const float* Wq = (const float*)d_in[2];
  const float* Wv = (const float*)d_in[3];
  float* out = (float*)d_out;
  char* ws = (char*)d_ws;

  unsigned short* Wt = (unsigned short*)ws;                       // 384KB
  unsigned short* Kb = (unsigned short*)(ws + (512u << 10));      // 2MB
  unsigned short* Qb = (unsigned short*)(ws + (512u << 10) + (2u << 20));
  unsigned short* Vt = (unsigned short*)(ws + (512u << 10) + (4u << 20));

  wtrans_kernel<<<48, 256, 0, stream>>>(Wk, Wq, Wv, Wt);
  proj_kernel<<<512, 256, 0, stream>>>(x, Wt, Kb, Qb, Vt);
  attn_kernel<<<512, 256, 0, stream>>>(Kb, Qb, Vt, out);
}

// Round 11
// 56.630 us; speedup vs baseline: 1.7957x; 1.7957x over previous
//
#include <hip/hip_runtime.h>
#include <hip/hip_bf16.h>

typedef short short8 __attribute__((ext_vector_type(8)));
typedef short short4v __attribute__((ext_vector_type(4)));
typedef float float4v __attribute__((ext_vector_type(4)));
typedef float f32x4 __attribute__((ext_vector_type(4)));

#define NEG_HUGE (-1e30f)
#define QK_SCALE 0.1803368801111204f  /* 0.125 * log2(e) */

__device__ __forceinline__ unsigned short f2bf(float f) {
  union { __hip_bfloat16 h; unsigned short u; } c;
  c.h = __float2bfloat16(f);
  return c.u;
}

#define MFMA16(a, b, c) __builtin_amdgcn_mfma_f32_16x16x32_bf16((a), (b), (c), 0, 0, 0)

// ---------------------------------------------------------------------------
// Kernel 0: W [1024][64] fp32 (x3) -> Wt [3][64][1024] bf16 (transposed).
// Wq additionally scaled by 0.125*log2(e) so attn works in exp2 domain.
// ---------------------------------------------------------------------------
__global__ __launch_bounds__(256) void wtrans_kernel(
    const float* __restrict__ Wk, const float* __restrict__ Wq,
    const float* __restrict__ Wv, unsigned short* __restrict__ Wt) {
  int mat = blockIdx.x >> 4, kb = blockIdx.x & 15;
  const float* W = (mat == 0) ? Wk : ((mat == 1) ? Wq : Wv);
  float qscale = (mat == 1) ? QK_SCALE : 1.0f;
  __shared__ float tile[64][65];
  int tid = threadIdx.x;
  int n = tid & 63, k0 = tid >> 6;
#pragma unroll
  for (int i = 0; i < 16; i++) {
    int k = i * 4 + k0;
    tile[k][n] = W[(kb * 64 + k) * 64 + n];
  }
  __syncthreads();
  int n2 = tid >> 2, c = tid & 3;
  unsigned short tmp[16];
#pragma unroll
  for (int j = 0; j < 16; j++) tmp[j] = f2bf(tile[c * 16 + j][n2] * qscale);
  unsigned short* dst = Wt + (mat * 64 + n2) * 1024 + kb * 64 + c * 16;
  *(short8*)dst = *(short8*)tmp;
  *(short8*)(dst + 8) = *(short8*)(tmp + 8);
}

// ---------------------------------------------------------------------------
// Kernel 1: projection v5 (m97-shaped). x[16384][1024] fp32 @ Wt[3][64][1024]
// bf16 -> Kb/Qb [16384][64] bf16, Vt (sigma-permuted). BM=64, BK=64, 512 thr
// = 8 waves (wm 0..3 rows x wn 0..1 col-groups of 96). grid 256 = 1 block/CU.
// Double-buffered LDS, XOR-swizzled (elem ^= (row&7)<<3, T2) so b128 frag
// reads are 2-way (free) with NO padding -> exactly 64KB LDS. Staging is
// coalesced; prefetch window 20 VGPRs; ONE barrier per iteration.
// ---------------------------------------------------------------------------
__global__ __launch_bounds__(512, 2) void proj_kernel(
    const float* __restrict__ x, const unsigned short* __restrict__ Wt,
    unsigned short* __restrict__ Kb, unsigned short* __restrict__ Qb,
    unsigned short* __restrict__ Vt) {
  __shared__ unsigned short x_l[2][64 * 64];    // 16 KB
  __shared__ unsigned short w_l[2][192 * 64];   // 48 KB
  int tid = threadIdx.x;
  int w = tid >> 6, lane = tid & 63;
  int wm = w >> 1, wn = w & 1;
  int g = lane >> 4, r = lane & 15;
  int row0 = blockIdx.x * 64;

  // staging map: x -> (row xr, 16B chunk xc16); W -> 3 chunks/thread
  int xr = tid >> 3, xc16 = tid & 7;
  const float* xp = &x[(size_t)(row0 + xr) * 1024 + xc16 * 8];
  int xelem = xr * 64 + ((xc16 * 8) ^ ((xr & 7) << 3));
  const unsigned short* wp[3];
  int welem[3];
#pragma unroll
  for (int i = 0; i < 3; i++) {
    int c = tid + i * 512;
    int wr = c >> 3, wc16 = c & 7;
    wp[i] = &Wt[(size_t)wr * 1024 + wc16 * 8];
    welem[i] = wr * 64 + ((wc16 * 8) ^ ((wr & 7) << 3));
  }
  int swz = (r & 7) << 3;

  f32x4 acc[6];
#pragma unroll
  for (int nf = 0; nf < 6; nf++) acc[nf] = (f32x4){0.f, 0.f, 0.f, 0.f};

  // prologue: load tile 0 into regs
  float4v xa = *(const float4v*)(xp);
  float4v xb = *(const float4v*)(xp + 4);
  short8 wv[3];
#pragma unroll
  for (int i = 0; i < 3; i++) wv[i] = *(const short8*)(wp[i]);

  for (int t = 0; t < 16; t++) {
    int buf = t & 1;
    // write staged regs -> LDS[buf]
    {
      unsigned short t8[8];
      t8[0] = f2bf(xa[0]); t8[1] = f2bf(xa[1]); t8[2] = f2bf(xa[2]); t8[3] = f2bf(xa[3]);
      t8[4] = f2bf(xb[0]); t8[5] = f2bf(xb[1]); t8[6] = f2bf(xb[2]); t8[7] = f2bf(xb[3]);
      *(short8*)&x_l[buf][xelem] = *(short8*)t8;
#pragma unroll
      for (int i = 0; i < 3; i++) *(short8*)&w_l[buf][welem[i]] = wv[i];
    }
    // issue next-tile loads (consumed next iter; latency hides under compute)
    if (t < 15) {
      int k0 = (t + 1) * 64;
      xa = *(const float4v*)(xp + k0);
      xb = *(const float4v*)(xp + k0 + 4);
#pragma unroll
      for (int i = 0; i < 3; i++) wv[i] = *(const short8*)(wp[i] + k0);
    }
    __syncthreads();
    // compute on LDS[buf]
#pragma unroll
    for (int ks = 0; ks < 2; ks++) {
      short8 af = *(short8*)&x_l[buf][(wm * 16 + r) * 64 + ((ks * 32 + g * 8) ^ swz)];
#pragma unroll
      for (int nf = 0; nf < 6; nf++) {
        short8 bf = *(short8*)&w_l[buf][(wn * 96 + nf * 16 + r) * 64 + ((ks * 32 + g * 8) ^ swz)];
        acc[nf] = MFMA16(af, bf, acc[nf]);
      }
    }
  }
  // epilogue: row = row0 + wm*16 + g*4 + reg, col = wn*96 + nf*16 + r
#pragma unroll
  for (int nf = 0; nf < 6; nf++) {
    int col = wn * 96 + nf * 16 + r;
    if (col < 128) {
      int mat = col >> 6, h = col & 63;
      unsigned short* dst = (mat == 0) ? Kb : Qb;
#pragma unroll
      for (int reg = 0; reg < 4; reg++) {
        int grow = row0 + wm * 16 + g * 4 + reg;
        dst[(size_t)grow * 64 + h] = f2bf(acc[nf][reg]);
      }
    } else {
      int h = col & 63;
      int grow0 = row0 + wm * 16 + g * 4;
      unsigned short t4[4];
#pragma unroll
      for (int reg = 0; reg < 4; reg++) t4[reg] = f2bf(acc[nf][reg]);
      // sigma permutation within the 64-row block (reg stays contiguous)
      int kv6 = grow0 & 63;
      int nfb = (kv6 >> 4) & 3, gb = (kv6 >> 2) & 3;
      int s0 = (nfb >> 1) * 32 + gb * 8 + (nfb & 1) * 4;
      size_t off = ((size_t)(grow0 >> 12) * 64 + h) * 4096 +
                   ((size_t)(grow0 & 4095) & ~(size_t)63) + s0;
      *(short4v*)&Vt[off] = *(short4v*)t4;
    }
  }
}

// ---------------------------------------------------------------------------
// Kernel 2: causal flash attention v8 (= v6 loop + colocation-balanced qt).
// grid 512, 256 thr = 4 waves kv-split (t%4==w), 32-row q-tile.
// Blocks bi and bi+256 co-reside on the same CU (observed round-robin
// dispatch); qt = (iq<64) ? 64+iq : 127-iq makes each colocated pair's
// ntiles sum exactly 65 -> uniform per-CU work, heavy blocks dispatched
// first. Swapped QK^T + swapped PV with pi-permuted V; P in registers.
// V loads issued AFTER QK^T so their latency hides under softmax.
// ---------------------------------------------------------------------------
__global__ __launch_bounds__(256, 3) void attn_kernel(
    const unsigned short* __restrict__ Kb, const unsigned short* __restrict__ Qb,
    const unsigned short* __restrict__ VtB, float* __restrict__ out) {
  __shared__ float O_l[4][32][68];
  __shared__ float st_l[4][32][2];
  int tid = threadIdx.x;
  int w = tid >> 6, lane = tid & 63;
  int g = lane >> 4, r = lane & 15;
  int bi = blockIdx.x;
  int b = bi & 3, iq = bi >> 2;           // iq 0..127
  int qt = (iq < 64) ? (64 + iq) : (127 - iq);
  int qabs = qt * 32;
  const unsigned short* Kp = Kb + (size_t)b * 4096 * 64;
  const unsigned short* Qp = Qb + (size_t)b * 4096 * 64;
  const unsigned short* Vp = VtB + (size_t)b * 64 * 4096;

  // Q B-operand frags: B[q=mf*16+r][k=h=ks*32+g*8+j]
  short8 qa[2][2];
#pragma unroll
  for (int mf = 0; mf < 2; mf++)
#pragma unroll
    for (int ks = 0; ks < 2; ks++)
      qa[mf][ks] = *(const short8*)&Qp[(size_t)(qabs + mf * 16 + r) * 64 + ks * 32 + g * 8];

  float m_st[2] = {NEG_HUGE, NEG_HUGE};
  float l_ln[2] = {0.f, 0.f};        // per-lane partial row sums
  f32x4 o[4][2];                      // o[nfh][mf]
#pragma unroll
  for (int nfh = 0; nfh < 4; nfh++)
#pragma unroll
    for (int mf = 0; mf < 2; mf++) o[nfh][mf] = (f32x4){0.f, 0.f, 0.f, 0.f};

  int ntiles = (qabs >> 6) + 1;
  for (int t = w; t < ntiles; t += 4) {
    int kvb = t << 6;
    // ---- S^T = K Q^T, K loaded JIT per ks-half ----
    f32x4 s[4][2];
#pragma unroll
    for (int nf = 0; nf < 4; nf++)
#pragma unroll
      for (int mf = 0; mf < 2; mf++) s[nf][mf] = (f32x4){0.f, 0.f, 0.f, 0.f};
#pragma unroll
    for (int ks = 0; ks < 2; ks++) {
      short8 kf[4];
#pragma unroll
      for (int nf = 0; nf < 4; nf++)
        kf[nf] = *(const short8*)&Kp[(size_t)(kvb + nf * 16 + r) * 64 + ks * 32 + g * 8];
#pragma unroll
      for (int nf = 0; nf < 4; nf++) {
        s[nf][0] = MFMA16(kf[nf], qa[0][ks], s[nf][0]);
        s[nf][1] = MFMA16(kf[nf], qa[1][ks], s[nf][1]);
      }
    }
    // ---- V A-fragments issued here: latency hides under softmax ----
    short8 vf[2][4];
#pragma unroll
    for (int ks = 0; ks < 2; ks++)
#pragma unroll
      for (int nfh = 0; nfh < 4; nfh++)
        vf[ks][nfh] = *(const short8*)&Vp[(size_t)(nfh * 16 + r) * 4096 + kvb + ks * 32 + g * 8];
    // ---- causal mask (final tile only) ----
    if (kvb + 63 > qabs) {
#pragma unroll
      for (int mf = 0; mf < 2; mf++) {
        int q = qabs + mf * 16 + r;
#pragma unroll
        for (int nf = 0; nf < 4; nf++)
#pragma unroll
          for (int reg = 0; reg < 4; reg++) {
            int kv = kvb + nf * 16 + g * 4 + reg;
            if (kv > q) s[nf][mf][reg] = NEG_HUGE;
          }
      }
    }
    // ---- row max (in-lane 16 + xor16/xor32), alpha ----
    float alpha[2];
#pragma unroll
    for (int mf = 0; mf < 2; mf++) {
      float m0 = fmaxf(fmaxf(fmaxf(s[0][mf][0], s[0][mf][1]), fmaxf(s[0][mf][2], s[0][mf][3])),
                       fmaxf(fmaxf(s[1][mf][0], s[1][mf][1]), fmaxf(s[1][mf][2], s[1][mf][3])));
      float m1 = fmaxf(fmaxf(fmaxf(s[2][mf][0], s[2][mf][1]), fmaxf(s[2][mf][2], s[2][mf][3])),
                       fmaxf(fmaxf(s[3][mf][0], s[3][mf][1]), fmaxf(s[3][mf][2], s[3][mf][3])));
      float m0a = fmaxf(m0, m1);
      m0a = fmaxf(m0a, __shfl_xor(m0a, 16));
      m0a = fmaxf(m0a, __shfl_xor(m0a, 32));
      float mn = fmaxf(m_st[mf], m0a);
      alpha[mf] = exp2f(m_st[mf] - mn);
      m_st[mf] = mn;
    }
    // ---- P = exp2(S - m) in-place; per-lane partial sums; rescale O ----
#pragma unroll
    for (int mf = 0; mf < 2; mf++) {
      float rs = 0.f;
#pragma unroll
      for (int nf = 0; nf < 4; nf++)
#pragma unroll
        for (int reg = 0; reg < 4; reg++) {
          float p = exp2f(s[nf][mf][reg] - m_st[mf]);
          s[nf][mf][reg] = p;
          rs += p;
        }
      l_ln[mf] = l_ln[mf] * alpha[mf] + rs;
#pragma unroll
      for (int nfh = 0; nfh < 4; nfh++)
#pragma unroll
        for (int reg = 0; reg < 4; reg++) o[nfh][mf][reg] *= alpha[mf];
    }
    // ---- pack P lane-locally (pi layout) and PV ----
#pragma unroll
    for (int ks = 0; ks < 2; ks++)
#pragma unroll
      for (int mf = 0; mf < 2; mf++) {
        union { unsigned u[4]; short8 v; } pb;
        asm("v_cvt_pk_bf16_f32 %0, %1, %2" : "=v"(pb.u[0]) : "v"(s[2 * ks][mf][0]), "v"(s[2 * ks][mf][1]));
        asm("v_cvt_pk_bf16_f32 %0, %1, %2" : "=v"(pb.u[1]) : "v"(s[2 * ks][mf][2]), "v"(s[2 * ks][mf][3]));
        asm("v_cvt_pk_bf16_f32 %0, %1, %2" : "=v"(pb.u[2]) : "v"(s[2 * ks + 1][mf][0]), "v"(s[2 * ks + 1][mf][1]));
        asm("v_cvt_pk_bf16_f32 %0, %1, %2" : "=v"(pb.u[3]) : "v"(s[2 * ks + 1][mf][2]), "v"(s[2 * ks + 1][mf][3]));
#pragma unroll
        for (int nfh = 0; nfh < 4; nfh++)
          o[nfh][mf] = MFMA16(vf[ks][nfh], pb.v, o[nfh][mf]);
      }
  }
  // ---- finalize l (deferred reduction) ----
#pragma unroll
  for (int mf = 0; mf < 2; mf++) {
    float s0 = l_ln[mf];
    s0 += __shfl_xor(s0, 16);
    s0 += __shfl_xor(s0, 32);
    l_ln[mf] = s0;
  }
  // ---- cross-wave merge: store [q][h] (q = mf*16+r, h = nfh*16+g*4+reg) ----
  __syncthreads();
#pragma unroll
  for (int nfh = 0; nfh < 4; nfh++)
#pragma unroll
    for (int mf = 0; mf < 2; mf++)
      *(f32x4*)&O_l[w][mf * 16 + r][nfh * 16 + g * 4] = o[nfh][mf];
  if (g == 0) {
#pragma unroll
    for (int mf = 0; mf < 2; mf++) {
      st_l[w][mf * 16 + r][0] = m_st[mf];
      st_l[w][mf * 16 + r][1] = l_ln[mf];
    }
  }
  __syncthreads();
  {
    int row = tid >> 3, cg = tid & 7;   // row = q (0..31), cg*8 = h block
    float mw[4], lw[4];
#pragma unroll
    for (int ww = 0; ww < 4; ww++) {
      mw[ww] = st_l[ww][row][0];
      lw[ww] = st_l[ww][row][1];
    }
    float mstar = fmaxf(fmaxf(mw[0], mw[1]), fmaxf(mw[2], mw[3]));
    float sc[4], lstar = 0.f;
#pragma unroll
    for (int ww = 0; ww < 4; ww++) { sc[ww] = exp2f(mw[ww] - mstar); lstar += sc[ww] * lw[ww]; }
    float inv = 1.0f / lstar;
    float a0[8];
#pragma unroll
    for (int cc = 0; cc < 8; cc++) a0[cc] = 0.f;
#pragma unroll
    for (int ww = 0; ww < 4; ww++) {
      f32x4 v0 = *(f32x4*)&O_l[ww][row][cg * 8];
      f32x4 v1 = *(f32x4*)&O_l[ww][row][cg * 8 + 4];
#pragma unroll
      for (int e = 0; e < 4; e++) { a0[e] += sc[ww] * v0[e]; a0[4 + e] += sc[ww] * v1[e]; }
    }
    float4v o0, o1;
#pragma unroll
    for (int e = 0; e < 4; e++) { o0[e] = a0[e] * inv; o1[e] = a0[4 + e] * inv; }
    float* op = &out[((size_t)b * 4096 + qabs + row) * 64 + cg * 8];
    *(float4v*)op = o0;
    *(float4v*)(op + 4) = o1;
  }
}

// ---------------------------------------------------------------------------
extern "C" void kernel_launch(void* const* d_in, const int* in_sizes, int n_in,
                              void* d_out, int out_size, void* d_ws, size_t ws_size,
                              hipStream_t stream) {
  (void)in_sizes; (void)n_in; (void)out_size; (void)ws_size;
  const float* x  = (const float*)d_in[0];
  const float* Wk = (const float*)d_in[1];
  const float* Wq = (const float*)d_in[2];
  const float* Wv = (const float*)d_in[3];
  float* out = (float*)d_out;
  char* ws = (char*)d_ws;

  unsigned short* Wt = (unsigned short*)ws;                       // 384KB
  unsigned short* Kb = (unsigned short*)(ws + (512u << 10));      // 2MB
  unsigned short* Qb = (unsigned short*)(ws + (512u << 10) + (2u << 20));
  unsigned short* Vt = (unsigned short*)(ws + (512u << 10) + (4u << 20));

  wtrans_kernel<<<48, 256, 0, stream>>>(Wk, Wq, Wv, Wt);
  proj_kernel<<<256, 512, 0, stream>>>(x, Wt, Kb, Qb, Vt);
  attn_kernel<<<512, 256, 0, stream>>>(Kb, Qb, Vt, out);
}